// Round 6
// baseline (159.407 us; speedup 1.0000x reference)
//
#include <hip/hip_runtime.h>
#include <hip/hip_bf16.h>
#include <cstdint>

typedef __attribute__((ext_vector_type(4))) float f32x4;
typedef __attribute__((ext_vector_type(8))) short bf16x8;

__device__ __forceinline__ ushort f2bf(float f) {
  unsigned u = __builtin_bit_cast(unsigned, f);
  u += 0x7fffu + ((u >> 16) & 1u);
  return (ushort)(u >> 16);
}
__device__ __forceinline__ float bf2f(ushort h) {
  unsigned u = ((unsigned)h) << 16;
  return __builtin_bit_cast(float, u);
}

__device__ __forceinline__ void gload_lds16(const ushort* g, ushort* l) {
  __builtin_amdgcn_global_load_lds(
      (const __attribute__((address_space(1))) unsigned int*)g,
      (__attribute__((address_space(3))) unsigned int*)l, 16, 0, 0);
}

__device__ __forceinline__ void hard_barrier() {
  __builtin_amdgcn_sched_barrier(0);
  __builtin_amdgcn_s_barrier();
  __builtin_amdgcn_sched_barrier(0);
}

template <int N>
__device__ __forceinline__ void wait_vm() {
  if constexpr (N == 0) asm volatile("s_waitcnt vmcnt(0)" ::: "memory");
  else if constexpr (N == 4) asm volatile("s_waitcnt vmcnt(4)" ::: "memory");
  else if constexpr (N == 8) asm volatile("s_waitcnt vmcnt(8)" ::: "memory");
  else static_assert(N < 0, "unsupported vmcnt");
}

// ---------- kernel 0a: x fp32 -> bf16 ----------
__global__ __launch_bounds__(256) void cvt_x_kernel(const float4* __restrict__ x,
                                                    ushort4* __restrict__ xb, int n4) {
  int stride = gridDim.x * blockDim.x;
  for (int i = blockIdx.x * blockDim.x + threadIdx.x; i < n4; i += stride) {
    float4 f = x[i];
    ushort4 o;
    o.x = f2bf(f.x); o.y = f2bf(f.y); o.z = f2bf(f.z); o.w = f2bf(f.w);
    xb[i] = o;
  }
}

// ---------- kernel 0b: W_qkv [1024][1536] f32 -> Wt [1536][1024] bf16 ----------
__global__ __launch_bounds__(256) void transpose_w_kernel(const float* __restrict__ W,
                                                          ushort* __restrict__ Wt) {
  __shared__ float tile[32][33];
  int n0 = blockIdx.x * 32;
  int k0 = blockIdx.y * 32;
  int tx = threadIdx.x;  // 0..31
  int ty = threadIdx.y;  // 0..7
  #pragma unroll
  for (int p = 0; p < 4; ++p) {
    int k = k0 + ty + p * 8;
    tile[ty + p * 8][tx] = W[(size_t)k * 1536 + n0 + tx];
  }
  __syncthreads();
  #pragma unroll
  for (int p = 0; p < 4; ++p) {
    int n = n0 + ty + p * 8;
    Wt[(size_t)n * 1024 + k0 + tx] = f2bf(tile[tx][ty + p * 8]);
  }
}

// ============================================================================
// Deep-prefetch 256x256 GEMM core. BK=32, 512 threads = 8 waves (2M x 4N),
// per-wave output 128x64 (MREP=8, NREP=4). LDS = 4 slots x 32KB = 128 KiB.
// Slot (ushorts): [A 256x32 = 8192 | B 256x32 = 8192]. 4 gloads/thread/tile.
// 2 phases per K-tile t:
//   ph1: read av[4](mh0)+bv[4]; stage A(t+3); barrier; 16 MFMA; barrier
//   ph2: read av[4](mh1);       stage B(t+3); vmcnt(8); barrier; 16 MFMA; barrier
// Prefetch distance 3 tiles: vmcnt(8) (= t+2's 4 + t+3's 4 in flight)
// guarantees tile t+1 landed; its loads were issued 4-6 phases earlier
// (~1400-2000 cy >> HBM ~900 cy) so the wait is normally a no-op.
// WAR: stage writes slot (t+3)&3, readers use t&3 (mod-4 distinct); the
// slot's previous reader (tile t-1) completed its ds_reads before the
// end-of-(t-1) barrier, which precedes ph1(t)'s stage issue. RAW: tile t's
// loads certified by the vmcnt at ph2(t-1). Tails: vmcnt(4) at t=NT-3,
// vmcnt(0) at t=NT-2 (prologue stages tiles 0..2; needs NT>=4).
// Bank swizzle (rule #21, linear gload_lds dest, pre-swizzled global source):
//   phys 16B slot = logical ^ ((row>>1)&3); reads conflict-free (r5: 0).
// ============================================================================
template <int LDA, int LDB, int NT>
__device__ __forceinline__ void gemm_core4(const ushort* __restrict__ A,
                                           const ushort* __restrict__ Bt,
                                           int row0, int col0, f32x4 acc[8][4],
                                           ushort* lds) {
  const int tid = threadIdx.x;
  const int l = tid & 63;
  const int wid = tid >> 6;
  const int fr = l & 15, fq = l >> 4;
  const int wr = wid >> 2, wc = wid & 3;

  // ---- staging (pre-swizzled global source) ----
  const int srow = tid >> 2;                     // 0..127
  const int lam = (tid & 3) ^ ((tid >> 3) & 3);  // logical 16B slot
  const ushort* aG = A + (size_t)(row0 + srow) * LDA + lam * 8;
  const ushort* bG = Bt + (size_t)(col0 + srow) * LDB + lam * 8;

  auto stageA = [&](int tt) {
    ushort* d = lds + (tt & 3) * 16384 + tid * 8;
    const ushort* s = aG + tt * 32;
    gload_lds16(s, d);
    gload_lds16(s + (size_t)128 * LDA, d + 4096);
  };
  auto stageB = [&](int tt) {
    ushort* d = lds + (tt & 3) * 16384 + 8192 + tid * 8;
    const ushort* s = bG + tt * 32;
    gload_lds16(s, d);
    gload_lds16(s + (size_t)128 * LDB, d + 4096);
  };

  // ---- fragment read offsets (ushort units within a slot) ----
  const int sig = fq ^ ((fr >> 1) & 3);  // phys 16B slot
  const int aOff = wr * 4096 + fr * 32 + sig * 8;
  const int bOff = 8192 + wc * 2048 + fr * 32 + sig * 8;

  auto mfma16 = [&](const bf16x8 av[4], const bf16x8 bv[4], int mh) {
    __builtin_amdgcn_s_setprio(1);
    #pragma unroll
    for (int mm = 0; mm < 4; ++mm)
      #pragma unroll
      for (int n = 0; n < 4; ++n)
        acc[mh * 4 + mm][n] =
            __builtin_amdgcn_mfma_f32_16x16x32_bf16(av[mm], bv[n], acc[mh * 4 + mm][n], 0, 0, 0);
    __builtin_amdgcn_s_setprio(0);
  };

  // ---- prologue: stage tiles 0..2 (12 loads); vmcnt(8) -> tile0 landed ----
  stageA(0); stageB(0); stageA(1); stageB(1); stageA(2); stageB(2);
  wait_vm<8>();
  hard_barrier();

  for (int t = 0; t < NT; ++t) {
    const ushort* sb = lds + (t & 3) * 16384;
    bf16x8 av[4], bv[4];

    // ph1: (mh0) -- A low half + B
    #pragma unroll
    for (int mm = 0; mm < 4; ++mm) av[mm] = *(const bf16x8*)(sb + aOff + mm * 512);
    #pragma unroll
    for (int n = 0; n < 4; ++n) bv[n] = *(const bf16x8*)(sb + bOff + n * 512);
    if (t + 3 < NT) stageA(t + 3);
    hard_barrier();
    mfma16(av, bv, 0);
    hard_barrier();

    // ph2: (mh1) -- A high half; bv held
    #pragma unroll
    for (int mm = 0; mm < 4; ++mm) av[mm] = *(const bf16x8*)(sb + aOff + 2048 + mm * 512);
    if (t + 3 < NT) {
      stageB(t + 3);
      wait_vm<8>();
    } else if (t + 3 == NT) {
      wait_vm<4>();
    } else if (t + 2 == NT) {
      wait_vm<0>();
    }
    hard_barrier();
    mfma16(av, bv, 1);
    hard_barrier();
  }
}

// ---------- kernel 1: qkv = x @ Wqkv, elu+1 on q,k cols, bf16 out ----------
__global__ __launch_bounds__(512, 1) void gemm_qkv_kernel(const ushort* __restrict__ xb,
                                                          const ushort* __restrict__ wt,
                                                          ushort* __restrict__ qkv) {
  __shared__ ushort lds[65536];  // 128 KiB
  f32x4 acc[8][4] = {};
  const int row0 = blockIdx.x * 256;
  const int col0 = blockIdx.y * 256;
  gemm_core4<1024, 1024, 32>(xb, wt, row0, col0, acc, lds);
  const int l = threadIdx.x & 63;
  const int wid = threadIdx.x >> 6;
  const int wr = wid >> 2, wc = wid & 3;
  const int fr = l & 15, fq = l >> 4;
  #pragma unroll
  for (int m = 0; m < 8; ++m) {
    #pragma unroll
    for (int n = 0; n < 4; ++n) {
      const int c = col0 + wc * 64 + n * 16 + fr;
      #pragma unroll
      for (int j = 0; j < 4; ++j) {
        const int r = row0 + wr * 128 + m * 16 + fq * 4 + j;
        float v = acc[m][n][j];
        if (c < 1024) v = (v > 0.f) ? (v + 1.f) : __expf(v);  // elu(v)+1
        qkv[(size_t)r * 1536 + c] = f2bf(v);
      }
    }
  }
}

// ---------- kernel 2: context partials ----------
__global__ __launch_bounds__(256) void ctx_kernel(const ushort* __restrict__ qkv,
                                                  float* __restrict__ part) {
  const int bh = blockIdx.x;     // 0..31
  const int split = blockIdx.y;  // 0..15
  const int b = bh >> 3, h = bh & 7;
  const int t = threadIdx.x;
  const int d0 = (t >> 4) * 4;
  const int e0 = (t & 15) * 4;
  __shared__ ushort ks[64][64];
  __shared__ ushort vs[64][64];
  float acc[4][4] = {};
  const int rowBase = b * 4096 + split * 256;
  for (int chunk = 0; chunk < 256; chunk += 64) {
    __syncthreads();
    #pragma unroll
    for (int p = 0; p < 2; ++p) {
      const int r = (t >> 3) + p * 32;
      const int c = (t & 7) * 8;
      const ushort* src = qkv + (size_t)(rowBase + chunk + r) * 1536;
      *(uint4*)&ks[r][c] = *(const uint4*)(src + 512 + h * 64 + c);
      *(uint4*)&vs[r][c] = *(const uint4*)(src + 1024 + h * 64 + c);
    }
    __syncthreads();
    for (int r = 0; r < 64; ++r) {
      ushort4 ku = *(const ushort4*)&ks[r][d0];
      ushort4 vu = *(const ushort4*)&vs[r][e0];
      float kk[4] = {bf2f(ku.x), bf2f(ku.y), bf2f(ku.z), bf2f(ku.w)};
      float vv[4] = {bf2f(vu.x), bf2f(vu.y), bf2f(vu.z), bf2f(vu.w)};
      #pragma unroll
      for (int i = 0; i < 4; ++i)
        #pragma unroll
        for (int j = 0; j < 4; ++j)
          acc[i][j] += kk[i] * vv[j];
    }
  }
  float* dst = part + ((size_t)split * 32 + bh) * 4096;
  #pragma unroll
  for (int i = 0; i < 4; ++i)
    #pragma unroll
    for (int j = 0; j < 4; ++j)
      dst[(d0 + i) * 64 + (e0 + j)] = acc[i][j];
}

// ---------- kernel 3: reduce partials ----------
__global__ __launch_bounds__(256) void ctx_reduce_kernel(const float* __restrict__ part,
                                                         float* __restrict__ ctx) {
  const int i = blockIdx.x * 256 + threadIdx.x;  // 131072 total
  float s = 0.f;
  #pragma unroll
  for (int sp = 0; sp < 16; ++sp) s += part[(size_t)sp * 131072 + i];
  ctx[i] = s;
}

// ---------- kernel 4: W_eff^T ----------
__global__ __launch_bounds__(256) void weff_kernel(const float* __restrict__ ctx,
                                                   const float* __restrict__ Wout,
                                                   ushort* __restrict__ weff) {
  const int bh = blockIdx.x;  // b*8+h
  const int h = bh & 7;
  const int m0 = blockIdx.y * 128;
  const int t = threadIdx.x;
  __shared__ float cs[64 * 64];
  __shared__ float ws[64][128];
  #pragma unroll
  for (int p = 0; p < 4; ++p) {
    const int idx = p * 1024 + t * 4;
    *(float4*)&cs[idx] = *(const float4*)&ctx[(size_t)bh * 4096 + idx];
  }
  #pragma unroll
  for (int p = 0; p < 8; ++p) {
    const int e = (t >> 5) + p * 8;
    const int c = (t & 31) * 4;
    *(float4*)&ws[e][c] = *(const float4*)&Wout[(size_t)(h * 64 + e) * 1024 + m0 + c];
  }
  __syncthreads();
  const int m = t & 127;
  const int dh = (t >> 7) * 32;
  float acc[32] = {};
  for (int e = 0; e < 64; ++e) {
    const float w = ws[e][m];
    #pragma unroll
    for (int i = 0; i < 32; ++i)
      acc[i] += cs[(dh + i) * 64 + e] * w;
  }
  ushort* dst = weff + ((size_t)(bh >> 3) * 1024 + m0 + m) * 512 + h * 64 + dh;
  #pragma unroll
  for (int i = 0; i < 32; ++i) dst[i] = f2bf(acc[i]);
}

// ---------- kernel 5: out = q @ W_eff^T + b_out (fp32 out) ----------
__global__ __launch_bounds__(512, 1) void gemm_out_kernel(const ushort* __restrict__ qkv,
                                                          const ushort* __restrict__ weff,
                                                          const float* __restrict__ bout,
                                                          float* __restrict__ out) {
  __shared__ ushort lds[65536];  // 128 KiB
  f32x4 acc[8][4] = {};
  const int row0 = blockIdx.x * 256;
  const int col0 = blockIdx.y * 256;
  const int b = row0 >> 12;  // row0 / 4096
  gemm_core4<1536, 512, 16>(qkv, weff + (size_t)b * 1024 * 512, row0, col0, acc, lds);
  const int l = threadIdx.x & 63;
  const int wid = threadIdx.x >> 6;
  const int wr = wid >> 2, wc = wid & 3;
  const int fr = l & 15, fq = l >> 4;
  #pragma unroll
  for (int m = 0; m < 8; ++m) {
    #pragma unroll
    for (int n = 0; n < 4; ++n) {
      const int c = col0 + wc * 64 + n * 16 + fr;
      const float bb = bout[c];
      #pragma unroll
      for (int j = 0; j < 4; ++j) {
        const int r = row0 + wr * 128 + m * 16 + fq * 4 + j;
        out[(size_t)r * 1024 + c] = acc[m][n][j] + bb;
      }
    }
  }
}

extern "C" void kernel_launch(void* const* d_in, const int* in_sizes, int n_in,
                              void* d_out, int out_size, void* d_ws, size_t ws_size,
                              hipStream_t stream) {
  const float* x    = (const float*)d_in[0];
  const float* Wqkv = (const float*)d_in[1];
  const float* Wout = (const float*)d_in[2];
  const float* bout = (const float*)d_in[3];
  float* out = (float*)d_out;
  char* ws = (char*)d_ws;

  // workspace layout (bytes)
  ushort* xb   = (ushort*)(ws);              // 16384*1024*2  = 33554432
  ushort* wt   = (ushort*)(ws + 33554432);   // 1536*1024*2   = 3145728
  ushort* qkv  = (ushort*)(ws + 36700160);   // 16384*1536*2  = 50331648
  float*  part = (float* )(ws + 87031808);   // 16*32*4096*4  = 8388608
  float*  ctx  = (float* )(ws + 95420416);   // 32*4096*4     = 524288
  ushort* weff = (ushort*)(ws + 95944704);   // 4*1024*512*2  = 4194304

  cvt_x_kernel<<<2048, 256, 0, stream>>>((const float4*)x, (ushort4*)xb, 16384 * 1024 / 4);
  transpose_w_kernel<<<dim3(48, 32), dim3(32, 8), 0, stream>>>(Wqkv, wt);
  gemm_qkv_kernel<<<dim3(64, 6), 512, 0, stream>>>(xb, wt, qkv);
  ctx_kernel<<<dim3(32, 16), 256, 0, stream>>>(qkv, part);
  ctx_reduce_kernel<<<512, 256, 0, stream>>>(part, ctx);
  weff_kernel<<<dim3(32, 8), 256, 0, stream>>>(ctx, Wout, weff);
  gemm_out_kernel<<<dim3(64, 4), 512, 0, stream>>>(qkv, weff, bout, out);
}

// Round 7
// 154.875 us; speedup vs baseline: 1.0293x; 1.0293x over previous
//
#include <hip/hip_runtime.h>
#include <hip/hip_bf16.h>
#include <cstdint>

typedef __attribute__((ext_vector_type(4))) float f32x4;
typedef __attribute__((ext_vector_type(8))) short bf16x8;

__device__ __forceinline__ ushort f2bf(float f) {
  unsigned u = __builtin_bit_cast(unsigned, f);
  u += 0x7fffu + ((u >> 16) & 1u);
  return (ushort)(u >> 16);
}
__device__ __forceinline__ float bf2f(ushort h) {
  unsigned u = ((unsigned)h) << 16;
  return __builtin_bit_cast(float, u);
}

__device__ __forceinline__ void gload_lds16(const ushort* g, ushort* l) {
  __builtin_amdgcn_global_load_lds(
      (const __attribute__((address_space(1))) unsigned int*)g,
      (__attribute__((address_space(3))) unsigned int*)l, 16, 0, 0);
}

__device__ __forceinline__ void hard_barrier() {
  __builtin_amdgcn_sched_barrier(0);
  __builtin_amdgcn_s_barrier();
  __builtin_amdgcn_sched_barrier(0);
}

template <int N>
__device__ __forceinline__ void wait_vm() {
  if constexpr (N == 0) asm volatile("s_waitcnt vmcnt(0)" ::: "memory");
  else if constexpr (N == 4) asm volatile("s_waitcnt vmcnt(4)" ::: "memory");
  else if constexpr (N == 8) asm volatile("s_waitcnt vmcnt(8)" ::: "memory");
  else static_assert(N < 0, "unsupported vmcnt");
}

// ---------- kernel 0a: x fp32 -> bf16 ----------
__global__ __launch_bounds__(256) void cvt_x_kernel(const float4* __restrict__ x,
                                                    ushort4* __restrict__ xb, int n4) {
  int stride = gridDim.x * blockDim.x;
  for (int i = blockIdx.x * blockDim.x + threadIdx.x; i < n4; i += stride) {
    float4 f = x[i];
    ushort4 o;
    o.x = f2bf(f.x); o.y = f2bf(f.y); o.z = f2bf(f.z); o.w = f2bf(f.w);
    xb[i] = o;
  }
}

// ---------- kernel 0b: W_qkv [1024][1536] f32 -> Wt [1536][1024] bf16 ----------
__global__ __launch_bounds__(256) void transpose_w_kernel(const float* __restrict__ W,
                                                          ushort* __restrict__ Wt) {
  __shared__ float tile[32][33];
  int n0 = blockIdx.x * 32;
  int k0 = blockIdx.y * 32;
  int tx = threadIdx.x;  // 0..31
  int ty = threadIdx.y;  // 0..7
  #pragma unroll
  for (int p = 0; p < 4; ++p) {
    int k = k0 + ty + p * 8;
    tile[ty + p * 8][tx] = W[(size_t)k * 1536 + n0 + tx];
  }
  __syncthreads();
  #pragma unroll
  for (int p = 0; p < 4; ++p) {
    int n = n0 + ty + p * 8;
    Wt[(size_t)n * 1024 + k0 + tx] = f2bf(tile[tx][ty + p * 8]);
  }
}

// ============================================================================
// Multi-block 128x128 GEMM core. BK=32, 256 threads = 4 waves (2M x 2N),
// per-wave output 64x64 (4x4 frags of 16x16). LDS = 4 slots x 16KB = 64 KiB
// -> 2 independent blocks/CU (__launch_bounds__(256,2)): cross-block overlap
// hides each block's vmcnt/barrier stalls (m114 mechanism).
// Slot (ushorts): [A 128x32 = 4096 | B 128x32 = 4096]. 4 gloads/thread/tile.
// Per K-tile t (one barrier per tile, compute contiguous — round-1's best
// measured schedule): stage(t+3); compute(t); vmcnt(8); barrier.
//   WAR: stage writes slot (t+3)&3 = (t-1)&3, whose reads finished before
//        the end-of-(t-1) barrier.  RAW: vmcnt(8) at end of t-1 leaves only
//        t+1,t+2's 8 loads outstanding -> tile t fully landed.
//   Tails: vmcnt(4) when t+3==NT, vmcnt(0) when t+2==NT. Needs NT>=4.
// Bank swizzle (rule #21, linear gload_lds dest, pre-swizzled global source),
// re-derived for 64B rows (4 x 16B slots): phys slot = logical ^ (row&3).
// Balance check: (row parity, phys) = 8 groups x 8 lanes x 4 banks = exactly
// 1 access/bank/cycle over the 8-cycle minimum -> conflict-free.
// ============================================================================
template <int LDA, int LDB, int NT>
__device__ __forceinline__ void gemm_tile_mb(const ushort* __restrict__ A,
                                             const ushort* __restrict__ Bt,
                                             int row0, int col0, f32x4 acc[4][4],
                                             ushort* lds) {
  const int tid = threadIdx.x;  // 0..255
  const int l = tid & 63;
  const int wid = tid >> 6;  // 0..3
  const int fr = l & 15, fq = l >> 4;
  const int wr = wid >> 1, wc = wid & 1;

  // ---- staging (pre-swizzled global source) ----
  const int srow = tid >> 2;                          // 0..63
  const int scol = ((tid & 3) ^ ((tid >> 2) & 3)) * 8;  // logical col of phys slot
  const ushort* aG = A + (size_t)(row0 + srow) * LDA + scol;
  const ushort* bG = Bt + (size_t)(col0 + srow) * LDB + scol;

  auto stage = [&](int tt) {
    ushort* d = lds + (tt & 3) * 8192 + tid * 8;
    const ushort* sA = aG + tt * 32;
    gload_lds16(sA, d);
    gload_lds16(sA + (size_t)64 * LDA, d + 2048);
    const ushort* sB = bG + tt * 32;
    gload_lds16(sB, d + 4096);
    gload_lds16(sB + (size_t)64 * LDB, d + 6144);
  };

  // ---- fragment read offsets (ushort units within a slot) ----
  const int phys = fq ^ (fr & 3);
  const int aOff = wr * 2048 + fr * 32 + phys * 8;
  const int bOff = 4096 + wc * 2048 + fr * 32 + phys * 8;

  auto compute = [&](int t) {
    const ushort* sb = lds + (t & 3) * 8192;
    bf16x8 av[4], bv[4];
    #pragma unroll
    for (int m = 0; m < 4; ++m) av[m] = *(const bf16x8*)(sb + aOff + m * 512);
    #pragma unroll
    for (int n = 0; n < 4; ++n) bv[n] = *(const bf16x8*)(sb + bOff + n * 512);
    __builtin_amdgcn_s_setprio(1);
    #pragma unroll
    for (int m = 0; m < 4; ++m)
      #pragma unroll
      for (int n = 0; n < 4; ++n)
        acc[m][n] = __builtin_amdgcn_mfma_f32_16x16x32_bf16(av[m], bv[n], acc[m][n], 0, 0, 0);
    __builtin_amdgcn_s_setprio(0);
  };

  // ---- prologue: stage tiles 0..2 (12 loads); vmcnt(8) -> tile0 landed ----
  stage(0); stage(1); stage(2);
  wait_vm<8>();
  hard_barrier();

  for (int t = 0; t < NT; ++t) {
    if (t + 3 < NT) stage(t + 3);
    compute(t);
    if (t + 3 < NT) {
      wait_vm<8>();
    } else if (t + 3 == NT) {
      wait_vm<4>();
    } else if (t + 2 == NT) {
      wait_vm<0>();
    }
    if (t + 1 < NT) hard_barrier();
  }
}

// ---------- kernel 1: qkv = x @ Wqkv, elu+1 on q,k cols, bf16 out ----------
__global__ __launch_bounds__(256, 2) void gemm_qkv_kernel(const ushort* __restrict__ xb,
                                                          const ushort* __restrict__ wt,
                                                          ushort* __restrict__ qkv) {
  __shared__ ushort lds[32768];  // 64 KiB
  f32x4 acc[4][4] = {};
  const int row0 = blockIdx.x * 128;
  const int col0 = blockIdx.y * 128;
  gemm_tile_mb<1024, 1024, 32>(xb, wt, row0, col0, acc, lds);
  const int l = threadIdx.x & 63;
  const int wid = threadIdx.x >> 6;
  const int wr = wid >> 1, wc = wid & 1;
  const int fr = l & 15, fq = l >> 4;
  #pragma unroll
  for (int m = 0; m < 4; ++m) {
    #pragma unroll
    for (int n = 0; n < 4; ++n) {
      const int c = col0 + wc * 64 + n * 16 + fr;
      #pragma unroll
      for (int j = 0; j < 4; ++j) {
        const int r = row0 + wr * 64 + m * 16 + fq * 4 + j;
        float v = acc[m][n][j];
        if (c < 1024) v = (v > 0.f) ? (v + 1.f) : __expf(v);  // elu(v)+1
        qkv[(size_t)r * 1536 + c] = f2bf(v);
      }
    }
  }
}

// ---------- kernel 2: context partials ----------
__global__ __launch_bounds__(256) void ctx_kernel(const ushort* __restrict__ qkv,
                                                  float* __restrict__ part) {
  const int bh = blockIdx.x;     // 0..31
  const int split = blockIdx.y;  // 0..15
  const int b = bh >> 3, h = bh & 7;
  const int t = threadIdx.x;
  const int d0 = (t >> 4) * 4;
  const int e0 = (t & 15) * 4;
  __shared__ ushort ks[64][64];
  __shared__ ushort vs[64][64];
  float acc[4][4] = {};
  const int rowBase = b * 4096 + split * 256;
  for (int chunk = 0; chunk < 256; chunk += 64) {
    __syncthreads();
    #pragma unroll
    for (int p = 0; p < 2; ++p) {
      const int r = (t >> 3) + p * 32;
      const int c = (t & 7) * 8;
      const ushort* src = qkv + (size_t)(rowBase + chunk + r) * 1536;
      *(uint4*)&ks[r][c] = *(const uint4*)(src + 512 + h * 64 + c);
      *(uint4*)&vs[r][c] = *(const uint4*)(src + 1024 + h * 64 + c);
    }
    __syncthreads();
    for (int r = 0; r < 64; ++r) {
      ushort4 ku = *(const ushort4*)&ks[r][d0];
      ushort4 vu = *(const ushort4*)&vs[r][e0];
      float kk[4] = {bf2f(ku.x), bf2f(ku.y), bf2f(ku.z), bf2f(ku.w)};
      float vv[4] = {bf2f(vu.x), bf2f(vu.y), bf2f(vu.z), bf2f(vu.w)};
      #pragma unroll
      for (int i = 0; i < 4; ++i)
        #pragma unroll
        for (int j = 0; j < 4; ++j)
          acc[i][j] += kk[i] * vv[j];
    }
  }
  float* dst = part + ((size_t)split * 32 + bh) * 4096;
  #pragma unroll
  for (int i = 0; i < 4; ++i)
    #pragma unroll
    for (int j = 0; j < 4; ++j)
      dst[(d0 + i) * 64 + (e0 + j)] = acc[i][j];
}

// ---------- kernel 3: reduce partials ----------
__global__ __launch_bounds__(256) void ctx_reduce_kernel(const float* __restrict__ part,
                                                         float* __restrict__ ctx) {
  const int i = blockIdx.x * 256 + threadIdx.x;  // 131072 total
  float s = 0.f;
  #pragma unroll
  for (int sp = 0; sp < 16; ++sp) s += part[(size_t)sp * 131072 + i];
  ctx[i] = s;
}

// ---------- kernel 4: W_eff^T ----------
__global__ __launch_bounds__(256) void weff_kernel(const float* __restrict__ ctx,
                                                   const float* __restrict__ Wout,
                                                   ushort* __restrict__ weff) {
  const int bh = blockIdx.x;  // b*8+h
  const int h = bh & 7;
  const int m0 = blockIdx.y * 128;
  const int t = threadIdx.x;
  __shared__ float cs[64 * 64];
  __shared__ float ws[64][128];
  #pragma unroll
  for (int p = 0; p < 4; ++p) {
    const int idx = p * 1024 + t * 4;
    *(float4*)&cs[idx] = *(const float4*)&ctx[(size_t)bh * 4096 + idx];
  }
  #pragma unroll
  for (int p = 0; p < 8; ++p) {
    const int e = (t >> 5) + p * 8;
    const int c = (t & 31) * 4;
    *(float4*)&ws[e][c] = *(const float4*)&Wout[(size_t)(h * 64 + e) * 1024 + m0 + c];
  }
  __syncthreads();
  const int m = t & 127;
  const int dh = (t >> 7) * 32;
  float acc[32] = {};
  for (int e = 0; e < 64; ++e) {
    const float w = ws[e][m];
    #pragma unroll
    for (int i = 0; i < 32; ++i)
      acc[i] += cs[(dh + i) * 64 + e] * w;
  }
  ushort* dst = weff + ((size_t)(bh >> 3) * 1024 + m0 + m) * 512 + h * 64 + dh;
  #pragma unroll
  for (int i = 0; i < 32; ++i) dst[i] = f2bf(acc[i]);
}

// ---------- kernel 5: out = q @ W_eff^T + b_out (fp32 out) ----------
__global__ __launch_bounds__(256, 2) void gemm_out_kernel(const ushort* __restrict__ qkv,
                                                          const ushort* __restrict__ weff,
                                                          const float* __restrict__ bout,
                                                          float* __restrict__ out) {
  __shared__ ushort lds[32768];  // 64 KiB
  f32x4 acc[4][4] = {};
  const int row0 = blockIdx.x * 128;
  const int col0 = blockIdx.y * 128;
  const int b = row0 >> 12;  // row0 / 4096
  gemm_tile_mb<1536, 512, 16>(qkv, weff + (size_t)b * 1024 * 512, row0, col0, acc, lds);
  const int l = threadIdx.x & 63;
  const int wid = threadIdx.x >> 6;
  const int wr = wid >> 1, wc = wid & 1;
  const int fr = l & 15, fq = l >> 4;
  #pragma unroll
  for (int m = 0; m < 4; ++m) {
    #pragma unroll
    for (int n = 0; n < 4; ++n) {
      const int c = col0 + wc * 64 + n * 16 + fr;
      const float bb = bout[c];
      #pragma unroll
      for (int j = 0; j < 4; ++j) {
        const int r = row0 + wr * 64 + m * 16 + fq * 4 + j;
        out[(size_t)r * 1024 + c] = acc[m][n][j] + bb;
      }
    }
  }
}

extern "C" void kernel_launch(void* const* d_in, const int* in_sizes, int n_in,
                              void* d_out, int out_size, void* d_ws, size_t ws_size,
                              hipStream_t stream) {
  const float* x    = (const float*)d_in[0];
  const float* Wqkv = (const float*)d_in[1];
  const float* Wout = (const float*)d_in[2];
  const float* bout = (const float*)d_in[3];
  float* out = (float*)d_out;
  char* ws = (char*)d_ws;

  // workspace layout (bytes)
  ushort* xb   = (ushort*)(ws);              // 16384*1024*2  = 33554432
  ushort* wt   = (ushort*)(ws + 33554432);   // 1536*1024*2   = 3145728
  ushort* qkv  = (ushort*)(ws + 36700160);   // 16384*1536*2  = 50331648
  float*  part = (float* )(ws + 87031808);   // 16*32*4096*4  = 8388608
  float*  ctx  = (float* )(ws + 95420416);   // 32*4096*4     = 524288
  ushort* weff = (ushort*)(ws + 95944704);   // 4*1024*512*2  = 4194304

  cvt_x_kernel<<<2048, 256, 0, stream>>>((const float4*)x, (ushort4*)xb, 16384 * 1024 / 4);
  transpose_w_kernel<<<dim3(48, 32), dim3(32, 8), 0, stream>>>(Wqkv, wt);
  gemm_qkv_kernel<<<dim3(128, 12), 256, 0, stream>>>(xb, wt, qkv);
  ctx_kernel<<<dim3(32, 16), 256, 0, stream>>>(qkv, part);
  ctx_reduce_kernel<<<512, 256, 0, stream>>>(part, ctx);
  weff_kernel<<<dim3(32, 8), 256, 0, stream>>>(ctx, Wout, weff);
  gemm_out_kernel<<<dim3(128, 8), 256, 0, stream>>>(qkv, weff, bout, out);
}

// Round 8
// 136.088 us; speedup vs baseline: 1.1714x; 1.1381x over previous
//
#include <hip/hip_runtime.h>
#include <hip/hip_bf16.h>
#include <cstdint>

typedef __attribute__((ext_vector_type(4))) float f32x4;
typedef __attribute__((ext_vector_type(8))) short bf16x8;

__device__ __forceinline__ ushort f2bf(float f) {
  unsigned u = __builtin_bit_cast(unsigned, f);
  u += 0x7fffu + ((u >> 16) & 1u);
  return (ushort)(u >> 16);
}

__device__ __forceinline__ void gload_lds16(const ushort* g, ushort* l) {
  __builtin_amdgcn_global_load_lds(
      (const __attribute__((address_space(1))) unsigned int*)g,
      (__attribute__((address_space(3))) unsigned int*)l, 16, 0, 0);
}

__device__ __forceinline__ void hard_barrier() {
  __builtin_amdgcn_sched_barrier(0);
  __builtin_amdgcn_s_barrier();
  __builtin_amdgcn_sched_barrier(0);
}

template <int N>
__device__ __forceinline__ void wait_vm() {
  if constexpr (N == 0) asm volatile("s_waitcnt vmcnt(0)" ::: "memory");
  else if constexpr (N == 2) asm volatile("s_waitcnt vmcnt(2)" ::: "memory");
  else if constexpr (N == 4) asm volatile("s_waitcnt vmcnt(4)" ::: "memory");
  else if constexpr (N == 6) asm volatile("s_waitcnt vmcnt(6)" ::: "memory");
  else static_assert(N < 0, "unsupported vmcnt");
}

__device__ __forceinline__ float elu1(float v) {
  return (v > 0.f) ? (v + 1.f) : __expf(v);
}

// ---------- kernel 0a: x fp32 -> bf16 ----------
__global__ __launch_bounds__(256) void cvt_x_kernel(const float4* __restrict__ x,
                                                    ushort4* __restrict__ xb, int n4) {
  int stride = gridDim.x * blockDim.x;
  for (int i = blockIdx.x * blockDim.x + threadIdx.x; i < n4; i += stride) {
    float4 f = x[i];
    ushort4 o;
    o.x = f2bf(f.x); o.y = f2bf(f.y); o.z = f2bf(f.z); o.w = f2bf(f.w);
    xb[i] = o;
  }
}

// ---------- kernel 0b: W_qkv [1024][1536] f32 -> Wt [1536][1024] bf16 ----------
__global__ __launch_bounds__(256) void transpose_w_kernel(const float* __restrict__ W,
                                                          ushort* __restrict__ Wt) {
  __shared__ float tile[32][33];
  int n0 = blockIdx.x * 32;
  int k0 = blockIdx.y * 32;
  int tx = threadIdx.x;  // 0..31
  int ty = threadIdx.y;  // 0..7
  #pragma unroll
  for (int p = 0; p < 4; ++p) {
    int k = k0 + ty + p * 8;
    tile[ty + p * 8][tx] = W[(size_t)k * 1536 + n0 + tx];
  }
  __syncthreads();
  #pragma unroll
  for (int p = 0; p < 4; ++p) {
    int n = n0 + ty + p * 8;
    Wt[(size_t)n * 1024 + k0 + tx] = f2bf(tile[tx][ty + p * 8]);
  }
}

// ============================================================================
// R1 core (measured best: 62 us, 831 TF, 0 bank conflicts): 128x256 tile,
// BK=64, 512 threads = 8 waves (2M x 4N), wave tile 64x64. 3 LDS slots of
// 48KB (A 16KB + B 32KB) = 144 KiB; single barrier per K-tile; counted
// vmcnt(6) (6 gloads/thread/tile); setprio around MFMA. Swizzle: phys 16B
// slot = logical ^ (row&7), staged via pre-swizzled global source (rule #21).
// ============================================================================
template <int LDA, int LDB, int NT>
__device__ __forceinline__ void gemm_core(const ushort* __restrict__ A,
                                          const ushort* __restrict__ Bt,
                                          int row0, int col0, f32x4 acc[4][4],
                                          ushort* lds) {
  const int tid = threadIdx.x;
  const int l = tid & 63;
  const int wid = tid >> 6;
  const int fr = l & 15;
  const int fq = l >> 4;
  const int wr = wid >> 2;
  const int wc = wid & 3;

  const int scol = ((l & 7) * 8) ^ (((l >> 3) & 7) * 8);
  const ushort* aS = A + (size_t)(row0 + (tid >> 3)) * LDA + scol;
  const ushort* bS = Bt + (size_t)(col0 + (tid >> 3)) * LDB + scol;

  int aRow[4], bRow[4], kx[2];
  #pragma unroll
  for (int m = 0; m < 4; ++m) aRow[m] = (wr * 64 + m * 16 + fr) * 64;
  #pragma unroll
  for (int n = 0; n < 4; ++n) bRow[n] = (wc * 64 + n * 16 + fr) * 64;
  #pragma unroll
  for (int ks = 0; ks < 2; ++ks) kx[ks] = (ks * 32 + fq * 8) ^ ((fr & 7) * 8);

  auto stage = [&](int t) {
    ushort* dst = lds + (t % 3) * 24576 + tid * 8;
    const int ko = t * 64;
    #pragma unroll
    for (int p = 0; p < 2; ++p)
      gload_lds16(aS + (size_t)(p * 64) * LDA + ko, dst + p * 4096);
    #pragma unroll
    for (int p = 0; p < 4; ++p)
      gload_lds16(bS + (size_t)(p * 64) * LDB + ko, dst + 8192 + p * 4096);
  };

  stage(0);
  stage(1);
  wait_vm<6>();
  hard_barrier();

  #pragma unroll
  for (int t = 0; t < NT; ++t) {
    if (t + 2 < NT) stage(t + 2);
    const ushort* aB = lds + (t % 3) * 24576;
    const ushort* bB = aB + 8192;
    #pragma unroll
    for (int ks = 0; ks < 2; ++ks) {
      bf16x8 av[4], bv[4];
      #pragma unroll
      for (int m = 0; m < 4; ++m) av[m] = *(const bf16x8*)&aB[aRow[m] + kx[ks]];
      #pragma unroll
      for (int n = 0; n < 4; ++n) bv[n] = *(const bf16x8*)&bB[bRow[n] + kx[ks]];
      __builtin_amdgcn_s_setprio(1);
      #pragma unroll
      for (int m = 0; m < 4; ++m)
        #pragma unroll
        for (int n = 0; n < 4; ++n)
          acc[m][n] = __builtin_amdgcn_mfma_f32_16x16x32_bf16(av[m], bv[n], acc[m][n], 0, 0, 0);
      __builtin_amdgcn_s_setprio(0);
    }
    if (t + 2 < NT) {
      wait_vm<6>();
      hard_barrier();
    } else if (t + 1 < NT) {
      wait_vm<0>();
      hard_barrier();
    }
  }
}

// ---------- kernel 1: qkv GEMM; epilogue emits q (elu+1), kT (elu+1), vT ----
// q   [16384][512] bf16 (row-major, n-major rows)
// kT  [b*8+h][64 d][4096 n] bf16   (elu+1 applied)
// vT  [b*8+h][64 e][4096 n] bf16
__global__ __launch_bounds__(512, 2) void gemm_qkv_kernel(const ushort* __restrict__ xb,
                                                          const ushort* __restrict__ wt,
                                                          ushort* __restrict__ q,
                                                          ushort* __restrict__ kT,
                                                          ushort* __restrict__ vT) {
  __shared__ ushort lds[73728];  // 144 KiB
  f32x4 acc[4][4] = {};
  const int row0 = blockIdx.x * 128;
  const int col0 = blockIdx.y * 256;
  gemm_core<1024, 1024, 16>(xb, wt, row0, col0, acc, lds);
  const int l = threadIdx.x & 63;
  const int wid = threadIdx.x >> 6;
  const int wr = wid >> 2, wc = wid & 3;
  const int fr = l & 15, fq = l >> 4;
  #pragma unroll
  for (int m = 0; m < 4; ++m) {
    #pragma unroll
    for (int n = 0; n < 4; ++n) {
      const int c = col0 + wc * 64 + n * 16 + fr;
      const int r0 = row0 + wr * 64 + m * 16 + fq * 4;  // j=0..3 consecutive rows
      if (c < 512) {
        #pragma unroll
        for (int j = 0; j < 4; ++j)
          q[(size_t)(r0 + j) * 512 + c] = f2bf(elu1(acc[m][n][j]));
      } else if (c < 1024) {
        const int d = c - 512;
        const int bh = (r0 >> 12) * 8 + (d >> 6);
        const int nn = r0 & 4095;
        ushort4 o;
        o.x = f2bf(elu1(acc[m][n][0]));
        o.y = f2bf(elu1(acc[m][n][1]));
        o.z = f2bf(elu1(acc[m][n][2]));
        o.w = f2bf(elu1(acc[m][n][3]));
        *(ushort4*)&kT[((size_t)bh * 64 + (d & 63)) * 4096 + nn] = o;
      } else {
        const int d = c - 1024;
        const int bh = (r0 >> 12) * 8 + (d >> 6);
        const int nn = r0 & 4095;
        ushort4 o;
        o.x = f2bf(acc[m][n][0]);
        o.y = f2bf(acc[m][n][1]);
        o.z = f2bf(acc[m][n][2]);
        o.w = f2bf(acc[m][n][3]);
        *(ushort4*)&vT[((size_t)bh * 64 + (d & 63)) * 4096 + nn] = o;
      }
    }
  }
}

// ---------- kernel 2: ctx partials via MFMA ----------
// part[sp][bh][d][e] = sum_{n in split} kT[bh][d][n] * vT[bh][e][n]
// grid (32 bh, 32 sp); 256 thr = 4 waves (2x2 of 32x32); NT=4 tiles of BK=32.
// All 4 tiles staged up-front into 4 write-once slots (no WAR); counted
// vmcnt 6/4/2/0 + barrier certifies each tile (2 gloads/thread/tile).
// Swizzle: R5's measured-0-conflict pattern (64B rows, phys slot =
// logical ^ ((row>>1)&3)), pre-swizzled global source.
__global__ __launch_bounds__(256) void ctx_mfma_kernel(const ushort* __restrict__ kT,
                                                       const ushort* __restrict__ vT,
                                                       float* __restrict__ part) {
  __shared__ ushort lds[16384];  // 4 slots x (A 64x32 + B 64x32) = 32 KiB
  const int bh = blockIdx.x;
  const int sp = blockIdx.y;
  const int tid = threadIdx.x;
  const int l = tid & 63, wid = tid >> 6;
  const int fr = l & 15, fq = l >> 4;
  const int wr = wid >> 1, wc = wid & 1;

  const size_t base = (size_t)bh * 64 * 4096 + sp * 128;
  const int srow = tid >> 2;                     // 0..63
  const int lam = (tid & 3) ^ ((tid >> 3) & 3);  // logical 16B slot for phys (tid&3)
  const ushort* aG = kT + base + (size_t)srow * 4096 + lam * 8;
  const ushort* bG = vT + base + (size_t)srow * 4096 + lam * 8;

  // prologue: stage all 4 tiles (write-once slots)
  #pragma unroll
  for (int t = 0; t < 4; ++t) {
    ushort* d = lds + t * 4096 + tid * 8;
    gload_lds16(aG + t * 32, d);
    gload_lds16(bG + t * 32, d + 2048);
  }

  const int sig = fq ^ ((fr >> 1) & 3);  // phys 16B slot for logical fq
  f32x4 acc[2][2] = {};

  auto compute = [&](int t) {
    const ushort* sb = lds + t * 4096;
    bf16x8 av[2], bv[2];
    #pragma unroll
    for (int mm = 0; mm < 2; ++mm)
      av[mm] = *(const bf16x8*)&sb[(wr * 32 + mm * 16 + fr) * 32 + sig * 8];
    #pragma unroll
    for (int nn = 0; nn < 2; ++nn)
      bv[nn] = *(const bf16x8*)&sb[2048 + (wc * 32 + nn * 16 + fr) * 32 + sig * 8];
    #pragma unroll
    for (int mm = 0; mm < 2; ++mm)
      #pragma unroll
      for (int nn = 0; nn < 2; ++nn)
        acc[mm][nn] = __builtin_amdgcn_mfma_f32_16x16x32_bf16(av[mm], bv[nn], acc[mm][nn], 0, 0, 0);
  };

  wait_vm<6>(); hard_barrier(); compute(0);
  wait_vm<4>(); hard_barrier(); compute(1);
  wait_vm<2>(); hard_barrier(); compute(2);
  wait_vm<0>(); hard_barrier(); compute(3);

  float* dst = part + ((size_t)sp * 32 + bh) * 4096;
  #pragma unroll
  for (int mm = 0; mm < 2; ++mm)
    #pragma unroll
    for (int nn = 0; nn < 2; ++nn)
      #pragma unroll
      for (int j = 0; j < 4; ++j)
        dst[(wr * 32 + mm * 16 + fq * 4 + j) * 64 + wc * 32 + nn * 16 + fr] = acc[mm][nn][j];
}

// ---------- kernel 3: reduce partials (32 splits) ----------
__global__ __launch_bounds__(256) void ctx_reduce_kernel(const float* __restrict__ part,
                                                         float* __restrict__ ctx) {
  const int i = blockIdx.x * 256 + threadIdx.x;  // 131072 total
  float s = 0.f;
  #pragma unroll
  for (int sp = 0; sp < 32; ++sp) s += part[(size_t)sp * 131072 + i];
  ctx[i] = s;
}

// ---------- kernel 4: W_eff^T[b][m][h*64+d] = sum_e ctx[b,h,d,e]*Wout[h*64+e][m] ----
__global__ __launch_bounds__(256) void weff_kernel(const float* __restrict__ ctx,
                                                   const float* __restrict__ Wout,
                                                   ushort* __restrict__ weff) {
  const int bh = blockIdx.x;  // b*8+h
  const int h = bh & 7;
  const int m0 = blockIdx.y * 128;
  const int t = threadIdx.x;
  __shared__ float cs[64 * 64];
  __shared__ float ws[64][128];
  #pragma unroll
  for (int p = 0; p < 4; ++p) {
    const int idx = p * 1024 + t * 4;
    *(float4*)&cs[idx] = *(const float4*)&ctx[(size_t)bh * 4096 + idx];
  }
  #pragma unroll
  for (int p = 0; p < 8; ++p) {
    const int e = (t >> 5) + p * 8;
    const int c = (t & 31) * 4;
    *(float4*)&ws[e][c] = *(const float4*)&Wout[(size_t)(h * 64 + e) * 1024 + m0 + c];
  }
  __syncthreads();
  const int m = t & 127;
  const int dh = (t >> 7) * 32;
  float acc[32] = {};
  for (int e = 0; e < 64; ++e) {
    const float w = ws[e][m];
    #pragma unroll
    for (int i = 0; i < 32; ++i)
      acc[i] += cs[(dh + i) * 64 + e] * w;
  }
  ushort* dst = weff + ((size_t)(bh >> 3) * 1024 + m0 + m) * 512 + h * 64 + dh;
  #pragma unroll
  for (int i = 0; i < 32; ++i) dst[i] = f2bf(acc[i]);
}

// ---------- kernel 5: out = q @ W_eff^T + b_out (fp32 out) ----------
__global__ __launch_bounds__(512, 2) void gemm_out_kernel(const ushort* __restrict__ q,
                                                          const ushort* __restrict__ weff,
                                                          const float* __restrict__ bout,
                                                          float* __restrict__ out) {
  __shared__ ushort lds[73728];  // 144 KiB
  f32x4 acc[4][4] = {};
  const int row0 = blockIdx.x * 128;
  const int col0 = blockIdx.y * 256;
  const int b = row0 >> 12;  // row0 / 4096
  gemm_core<512, 512, 8>(q, weff + (size_t)b * 1024 * 512, row0, col0, acc, lds);
  const int l = threadIdx.x & 63;
  const int wid = threadIdx.x >> 6;
  const int wr = wid >> 2, wc = wid & 3;
  const int fr = l & 15, fq = l >> 4;
  #pragma unroll
  for (int m = 0; m < 4; ++m) {
    #pragma unroll
    for (int n = 0; n < 4; ++n) {
      const int c = col0 + wc * 64 + n * 16 + fr;
      const float bb = bout[c];
      #pragma unroll
      for (int j = 0; j < 4; ++j) {
        const int r = row0 + wr * 64 + m * 16 + fq * 4 + j;
        out[(size_t)r * 1024 + c] = acc[m][n][j] + bb;
      }
    }
  }
}

extern "C" void kernel_launch(void* const* d_in, const int* in_sizes, int n_in,
                              void* d_out, int out_size, void* d_ws, size_t ws_size,
                              hipStream_t stream) {
  const float* x    = (const float*)d_in[0];
  const float* Wqkv = (const float*)d_in[1];
  const float* Wout = (const float*)d_in[2];
  const float* bout = (const float*)d_in[3];
  float* out = (float*)d_out;
  char* ws = (char*)d_ws;

  // workspace layout (bytes). part aliases xb (xb dead after gemm_qkv).
  ushort* xb   = (ushort*)(ws);              // 16384*1024*2  = 33554432
  float*  part = (float* )(ws);              // 32*32*4096*4  = 16777216 (alias)
  ushort* wt   = (ushort*)(ws + 33554432);   // 1536*1024*2   = 3145728
  ushort* q    = (ushort*)(ws + 36700160);   // 16384*512*2   = 16777216
  ushort* kT   = (ushort*)(ws + 53477376);   // 32*64*4096*2  = 16777216
  ushort* vT   = (ushort*)(ws + 70254592);   // 32*64*4096*2  = 16777216
  float*  ctx  = (float* )(ws + 87031808);   // 32*4096*4     = 524288
  ushort* weff = (ushort*)(ws + 87556096);   // 4*1024*512*2  = 4194304

  cvt_x_kernel<<<2048, 256, 0, stream>>>((const float4*)x, (ushort4*)xb, 16384 * 1024 / 4);
  transpose_w_kernel<<<dim3(48, 32), dim3(32, 8), 0, stream>>>(Wqkv, wt);
  gemm_qkv_kernel<<<dim3(128, 6), 512, 0, stream>>>(xb, wt, q, kT, vT);
  ctx_mfma_kernel<<<dim3(32, 32), 256, 0, stream>>>(kT, vT, part);
  ctx_reduce_kernel<<<512, 256, 0, stream>>>(part, ctx);
  weff_kernel<<<dim3(32, 8), 256, 0, stream>>>(ctx, Wout, weff);
  gemm_out_kernel<<<dim3(128, 4), 512, 0, stream>>>(q, weff, bout, out);
}